// Round 1
// baseline (5356.248 us; speedup 1.0000x reference)
//
#include <hip/hip_runtime.h>
#include <hip/hip_bf16.h>
#include <math.h>

#define NN 20000
#define NE 160000
#define NG 256
#define HDIM 128
#define EPSV 1e-5f

__device__ __forceinline__ float sigmoidf_(float x){ return 1.0f/(1.0f+__expf(-x)); }
__device__ __forceinline__ float softplusf_(float x){ return fmaxf(x,0.0f) + log1pf(__expf(-fabsf(x))); }

// h = relu(x @ W_node + b_node); also initialize hacc = h (residual base for layer 0)
__global__ __launch_bounds__(256) void k_embed_node(
    const float* __restrict__ x, const float* __restrict__ W, const float* __restrict__ b,
    float* __restrict__ h, float* __restrict__ hacc)
{
  int i = blockIdx.x*256 + threadIdx.x;
  if (i >= NN*HDIM) return;
  int n = i >> 7, c = i & 127;
  float acc = b[c];
  const float* xr = x + n*10;
  #pragma unroll
  for (int k=0;k<10;k++) acc = fmaf(xr[k], W[k*HDIM+c], acc);
  acc = fmaxf(acc, 0.0f);
  h[i] = acc; hacc[i] = acc;
}

// One CGConv layer's edge work: z=[h[dst]|h[src]|e], msg = sigmoid(z@Wf+bf)*softplus(z@Ws+bs),
// atomicAdd msg into hacc[dst]. e is recomputed on the fly from edge_attr (K=3).
// Tile: 32 edges/block, 256 threads: thread (g=t>>7, c=t&127) does 16 edges x both gates x column c.
__global__ __launch_bounds__(256) void k_cgconv(
    const float* __restrict__ h, const float* __restrict__ eattr,
    const float* __restrict__ W_edge, const float* __restrict__ b_edge,
    const int* __restrict__ ei,
    const float* __restrict__ Wf, const float* __restrict__ bf,
    const float* __restrict__ Ws, const float* __restrict__ bs,
    float* __restrict__ hacc)
{
  __shared__ float4 z4[32*96];     // [edge][k4] : 384 floats per edge = 48KB
  __shared__ int s_src[32], s_dst[32];
  int t = threadIdx.x;
  int e0 = blockIdx.x * 32;
  if (t < 32) { s_src[t] = ei[e0+t]; s_dst[t] = ei[NE + e0 + t]; }
  __syncthreads();
  // stage z: 3072 float4 slots, cooperatively
  for (int i = t; i < 32*96; i += 256) {
    int el = i / 96;
    int k4 = i - el*96;
    float4 v;
    if (k4 < 32) {
      v = *(const float4*)&h[(size_t)s_dst[el]*HDIM + k4*4];
    } else if (k4 < 64) {
      v = *(const float4*)&h[(size_t)s_src[el]*HDIM + (k4-32)*4];
    } else {
      int cc = (k4-64)*4;
      int eg = e0 + el;
      float a0 = eattr[eg*3+0], a1 = eattr[eg*3+1], a2 = eattr[eg*3+2];
      float4 w0 = *(const float4*)&W_edge[0*HDIM+cc];
      float4 w1 = *(const float4*)&W_edge[1*HDIM+cc];
      float4 w2 = *(const float4*)&W_edge[2*HDIM+cc];
      float4 bb = *(const float4*)&b_edge[cc];
      v.x = fmaxf(fmaf(a0,w0.x,fmaf(a1,w1.x,fmaf(a2,w2.x,bb.x))), 0.0f);
      v.y = fmaxf(fmaf(a0,w0.y,fmaf(a1,w1.y,fmaf(a2,w2.y,bb.y))), 0.0f);
      v.z = fmaxf(fmaf(a0,w0.z,fmaf(a1,w1.z,fmaf(a2,w2.z,bb.z))), 0.0f);
      v.w = fmaxf(fmaf(a0,w0.w,fmaf(a1,w1.w,fmaf(a2,w2.w,bb.w))), 0.0f);
    }
    z4[i] = v;
  }
  __syncthreads();
  int c = t & 127;
  int g = t >> 7;                 // edge half: edges g*16 .. g*16+15
  float accf[16], accs[16];
  float bfv = bf[c], bsv = bs[c];
  #pragma unroll
  for (int e=0;e<16;e++){ accf[e]=bfv; accs[e]=bsv; }
  const float4* zb = &z4[(g*16)*96];
  const float* wfc = Wf + c;
  const float* wsc = Ws + c;
  for (int k4=0;k4<96;k4++){
    int kk = (k4*4)*HDIM;
    float wf0 = wfc[kk], wf1 = wfc[kk+HDIM], wf2 = wfc[kk+2*HDIM], wf3 = wfc[kk+3*HDIM];
    float ws0 = wsc[kk], ws1 = wsc[kk+HDIM], ws2 = wsc[kk+2*HDIM], ws3 = wsc[kk+3*HDIM];
    #pragma unroll
    for (int e=0;e<16;e++){
      float4 zv = zb[e*96 + k4];  // broadcast across wave lanes
      accf[e] = fmaf(zv.x,wf0,fmaf(zv.y,wf1,fmaf(zv.z,wf2,fmaf(zv.w,wf3,accf[e]))));
      accs[e] = fmaf(zv.x,ws0,fmaf(zv.y,ws1,fmaf(zv.z,ws2,fmaf(zv.w,ws3,accs[e]))));
    }
  }
  #pragma unroll
  for (int e=0;e<16;e++){
    float msg = sigmoidf_(accf[e]) * softplusf_(accs[e]);
    atomicAdd(&hacc[(size_t)s_dst[g*16+e]*HDIM + c], msg);
  }
}

// h_new = relu(BN(hacc)) (+ h_in if addres); write into h and hacc (next layer's residual base)
__global__ __launch_bounds__(256) void k_bn(
    const float* __restrict__ hacc, const float* __restrict__ hin,
    const float* __restrict__ gam, const float* __restrict__ bet,
    const float* __restrict__ mu, const float* __restrict__ var,
    float* __restrict__ hout, float* __restrict__ haccout, int addres)
{
  int i = blockIdx.x*256 + threadIdx.x;
  if (i >= NN*HDIM) return;
  int c = i & 127;
  float scale = gam[c]*rsqrtf(var[c]+EPSV);
  float tv = (hacc[i]-mu[c])*scale + bet[c];
  tv = fmaxf(tv, 0.0f);
  if (addres) tv += hin[i];
  hout[i] = tv; haccout[i] = tv;
}

__global__ __launch_bounds__(256) void k_pool(
    const float* __restrict__ h, const int* __restrict__ batch,
    float* __restrict__ psum, float* __restrict__ pmax, float* __restrict__ pcnt)
{
  int i = blockIdx.x*256 + threadIdx.x;
  if (i >= NN*HDIM) return;
  int n = i >> 7, c = i & 127;
  int b = batch[n];
  float v = h[i];
  atomicAdd(&psum[b*HDIM+c], v);
  atomicMax((unsigned int*)&pmax[b*HDIM+c], __float_as_uint(v));  // valid: v >= 0
  if (c == 0) atomicAdd(&pcnt[b], 1.0f);
}

// g = [mean|max|sum]; g1 = relu(BN1(g @ W1 + b1))   [256,256]
__global__ __launch_bounds__(256) void k_mlp1(
    const float* __restrict__ psum, const float* __restrict__ pmax, const float* __restrict__ pcnt,
    const float* __restrict__ W1, const float* __restrict__ b1,
    const float* __restrict__ g1g, const float* __restrict__ g1b,
    const float* __restrict__ g1m, const float* __restrict__ g1v,
    float* __restrict__ out)
{
  int i = blockIdx.x*256 + threadIdx.x;
  int g = i >> 8, c = i & 255;
  float inv = 1.0f / fmaxf(pcnt[g], 1.0f);
  float acc = b1[c];
  for (int k=0;k<HDIM;k++) acc = fmaf(psum[g*HDIM+k]*inv, W1[k*256+c], acc);
  for (int k=0;k<HDIM;k++) acc = fmaf(pmax[g*HDIM+k],     W1[(HDIM+k)*256+c], acc);
  for (int k=0;k<HDIM;k++) acc = fmaf(psum[g*HDIM+k],     W1[(2*HDIM+k)*256+c], acc);
  float scale = g1g[c]*rsqrtf(g1v[c]+EPSV);
  acc = (acc - g1m[c])*scale + g1b[c];
  out[i] = fmaxf(acc, 0.0f);
}

// g2 = relu(BN2(g1 @ W2 + b2))   [256,128]
__global__ __launch_bounds__(256) void k_mlp2(
    const float* __restrict__ g1, const float* __restrict__ W2, const float* __restrict__ b2,
    const float* __restrict__ g2g, const float* __restrict__ g2b,
    const float* __restrict__ g2m, const float* __restrict__ g2v,
    float* __restrict__ out)
{
  int i = blockIdx.x*256 + threadIdx.x;
  int g = i >> 7, c = i & 127;
  float acc = b2[c];
  for (int k=0;k<256;k++) acc = fmaf(g1[g*256+k], W2[k*HDIM+c], acc);
  float scale = g2g[c]*rsqrtf(g2v[c]+EPSV);
  acc = (acc - g2m[c])*scale + g2b[c];
  out[i] = fmaxf(acc, 0.0f);
}

// g3 = relu(g2 @ W3 + b3)   [256,64]
__global__ __launch_bounds__(256) void k_mlp3(
    const float* __restrict__ g2, const float* __restrict__ W3, const float* __restrict__ b3,
    float* __restrict__ out)
{
  int i = blockIdx.x*256 + threadIdx.x;
  int g = i >> 6, c = i & 63;
  float acc = b3[c];
  for (int k=0;k<HDIM;k++) acc = fmaf(g2[g*HDIM+k], W3[k*64+c], acc);
  out[i] = fmaxf(acc, 0.0f);
}

__global__ __launch_bounds__(256) void k_heads(
    const float* __restrict__ g3,
    const float* __restrict__ Wv, const float* __restrict__ bv,
    const float* __restrict__ We, const float* __restrict__ be,
    const float* __restrict__ Wd, const float* __restrict__ bd,
    const float* __restrict__ Wh, const float* __restrict__ bh,
    float* __restrict__ out)
{
  int g = blockIdx.x*256 + threadIdx.x;
  if (g >= NG) return;
  float a0=bv[0], a1=be[0], a2=bd[0], a3=bh[0];
  for (int k=0;k<64;k++){
    float xv = g3[g*64+k];
    a0 = fmaf(xv, Wv[k], a0);
    a1 = fmaf(xv, We[k], a1);
    a2 = fmaf(xv, Wd[k], a2);
    a3 = fmaf(xv, Wh[k], a3);
  }
  out[g] = a0; out[NG+g] = a1; out[2*NG+g] = a2; out[3*NG+g] = a3;
}

extern "C" void kernel_launch(void* const* d_in, const int* in_sizes, int n_in,
                              void* d_out, int out_size, void* d_ws, size_t ws_size,
                              hipStream_t stream)
{
  const float* x         = (const float*)d_in[0];
  const float* edge_attr = (const float*)d_in[1];
  const int*   ei        = (const int*)d_in[2];
  const int*   batch     = (const int*)d_in[3];
  const float* W_node    = (const float*)d_in[4];
  const float* b_node    = (const float*)d_in[5];
  const float* W_edge    = (const float*)d_in[6];
  const float* b_edge    = (const float*)d_in[7];
  const float* Wf        = (const float*)d_in[8];
  const float* bf        = (const float*)d_in[9];
  const float* Ws        = (const float*)d_in[10];
  const float* bs        = (const float*)d_in[11];
  const float* bn_g      = (const float*)d_in[12];
  const float* bn_b      = (const float*)d_in[13];
  const float* bn_m      = (const float*)d_in[14];
  const float* bn_v      = (const float*)d_in[15];
  const float* W1        = (const float*)d_in[16];
  const float* b1        = (const float*)d_in[17];
  const float* bn1_g     = (const float*)d_in[18];
  const float* bn1_b     = (const float*)d_in[19];
  const float* bn1_m     = (const float*)d_in[20];
  const float* bn1_v     = (const float*)d_in[21];
  const float* W2        = (const float*)d_in[22];
  const float* b2        = (const float*)d_in[23];
  const float* bn2_g     = (const float*)d_in[24];
  const float* bn2_b     = (const float*)d_in[25];
  const float* bn2_m     = (const float*)d_in[26];
  const float* bn2_v     = (const float*)d_in[27];
  const float* W3        = (const float*)d_in[28];
  const float* b3        = (const float*)d_in[29];
  const float* Wv        = (const float*)d_in[30];
  const float* bv        = (const float*)d_in[31];
  const float* W_en      = (const float*)d_in[32];
  const float* b_en      = (const float*)d_in[33];
  const float* Wd        = (const float*)d_in[34];
  const float* bd        = (const float*)d_in[35];
  const float* Wh        = (const float*)d_in[36];
  const float* bh        = (const float*)d_in[37];

  float* ws   = (float*)d_ws;
  float* h    = ws;                         // 2,560,000
  float* hacc = ws + 2560000;               // 2,560,000
  float* psum = ws + 5120000;               // 32768
  float* pmax = psum + 32768;               // 32768
  float* pcnt = pmax + 32768;               // 256
  float* g1   = pcnt + 256;                 // 65536
  float* g2   = g1 + 65536;                 // 32768
  float* g3   = g2 + 32768;                 // 16384

  k_embed_node<<<(NN*HDIM+255)/256, 256, 0, stream>>>(x, W_node, b_node, h, hacc);
  hipMemsetAsync(psum, 0, (size_t)(32768+32768+256)*sizeof(float), stream);

  for (int i=0;i<10;i++){
    k_cgconv<<<NE/32, 256, 0, stream>>>(h, edge_attr, W_edge, b_edge, ei,
        Wf + (size_t)i*384*HDIM, bf + i*HDIM, Ws + (size_t)i*384*HDIM, bs + i*HDIM, hacc);
    k_bn<<<(NN*HDIM+255)/256, 256, 0, stream>>>(hacc, h,
        bn_g + i*HDIM, bn_b + i*HDIM, bn_m + i*HDIM, bn_v + i*HDIM, h, hacc, i&1);
  }

  k_pool<<<(NN*HDIM+255)/256, 256, 0, stream>>>(h, batch, psum, pmax, pcnt);
  k_mlp1<<<(NG*256)/256, 256, 0, stream>>>(psum, pmax, pcnt, W1, b1, bn1_g, bn1_b, bn1_m, bn1_v, g1);
  k_mlp2<<<(NG*128)/256, 256, 0, stream>>>(g1, W2, b2, bn2_g, bn2_b, bn2_m, bn2_v, g2);
  k_mlp3<<<(NG*64)/256, 256, 0, stream>>>(g2, W3, b3, g3);
  k_heads<<<1, 256, 0, stream>>>(g3, Wv, bv, W_en, b_en, Wd, bd, Wh, bh, (float*)d_out);
}

// Round 2
// 3135.749 us; speedup vs baseline: 1.7081x; 1.7081x over previous
//
#include <hip/hip_runtime.h>
#include <hip/hip_bf16.h>
#include <math.h>

#define NN 20000
#define NE 160000
#define NG 256
#define HDIM 128
#define EPSV 1e-5f

__device__ __forceinline__ float sigmoidf_(float x){ return 1.0f/(1.0f+__expf(-x)); }
__device__ __forceinline__ float softplusf_(float x){ return fmaxf(x,0.0f) + log1pf(__expf(-fabsf(x))); }

// h = relu(x @ W_node + b_node); also initialize hacc = h (residual base for layer 0)
__global__ __launch_bounds__(256) void k_embed_node(
    const float* __restrict__ x, const float* __restrict__ W, const float* __restrict__ b,
    float* __restrict__ h, float* __restrict__ hacc)
{
  int i = blockIdx.x*256 + threadIdx.x;
  if (i >= NN*HDIM) return;
  int n = i >> 7, c = i & 127;
  float acc = b[c];
  const float* xr = x + n*10;
  #pragma unroll
  for (int k=0;k<10;k++) acc = fmaf(xr[k], W[k*HDIM+c], acc);
  acc = fmaxf(acc, 0.0f);
  h[i] = acc; hacc[i] = acc;
}

// Per-node projections for one layer:
//   Af = h@Wf1 + bf, Bf = h@Wf2, As = h@Ws1 + bs, Bs = h@Ws2
// (Wf1 = rows 0..127 of Wf, Wf2 = rows 128..255; e-part rows 256..383 handled per edge)
// Tile: 16 nodes/block; thread (g=t>>7, c=t&127) does 8 nodes x 4 projections.
__global__ __launch_bounds__(256) void k_nodeproj(
    const float* __restrict__ h,
    const float* __restrict__ Wf, const float* __restrict__ bfv,
    const float* __restrict__ Ws, const float* __restrict__ bsv,
    float* __restrict__ Af, float* __restrict__ Bf,
    float* __restrict__ As, float* __restrict__ Bs)
{
  __shared__ float4 ht[16*32];   // [node][k4] : 128 floats per node = 8KB
  int t = threadIdx.x;
  int n0 = blockIdx.x * 16;
  for (int i = t; i < 16*32; i += 256) {
    int nl = i >> 5, k4 = i & 31;
    ht[i] = *(const float4*)&h[(size_t)(n0+nl)*HDIM + k4*4];
  }
  __syncthreads();
  int c = t & 127, g = t >> 7;
  float af[8], bfa[8], as_[8], bsa[8];
  float bf0 = bfv[c], bs0 = bsv[c];
  #pragma unroll
  for (int e=0;e<8;e++){ af[e]=bf0; bfa[e]=0.0f; as_[e]=bs0; bsa[e]=0.0f; }
  const float* wA = Wf + c;            // Wf1 col c
  const float* wB = Wf + 128*HDIM + c; // Wf2 col c
  const float* sA = Ws + c;
  const float* sB = Ws + 128*HDIM + c;
  const float4* hb = &ht[(g*8)*32];
  for (int k4=0;k4<32;k4++){
    int kk = (k4*4)*HDIM;
    float a0=wA[kk], a1=wA[kk+HDIM], a2=wA[kk+2*HDIM], a3=wA[kk+3*HDIM];
    float b0=wB[kk], b1=wB[kk+HDIM], b2=wB[kk+2*HDIM], b3=wB[kk+3*HDIM];
    float c0=sA[kk], c1=sA[kk+HDIM], c2=sA[kk+2*HDIM], c3=sA[kk+3*HDIM];
    float d0=sB[kk], d1=sB[kk+HDIM], d2=sB[kk+2*HDIM], d3=sB[kk+3*HDIM];
    #pragma unroll
    for (int e=0;e<8;e++){
      float4 hv = hb[e*32 + k4];   // broadcast within half-block
      af[e]  = fmaf(hv.x,a0,fmaf(hv.y,a1,fmaf(hv.z,a2,fmaf(hv.w,a3,af[e]))));
      bfa[e] = fmaf(hv.x,b0,fmaf(hv.y,b1,fmaf(hv.z,b2,fmaf(hv.w,b3,bfa[e]))));
      as_[e] = fmaf(hv.x,c0,fmaf(hv.y,c1,fmaf(hv.z,c2,fmaf(hv.w,c3,as_[e]))));
      bsa[e] = fmaf(hv.x,d0,fmaf(hv.y,d1,fmaf(hv.z,d2,fmaf(hv.w,d3,bsa[e]))));
    }
  }
  #pragma unroll
  for (int e=0;e<8;e++){
    size_t n = (size_t)(n0 + g*8 + e)*HDIM + c;
    Af[n]=af[e]; Bf[n]=bfa[e]; As[n]=as_[e]; Bs[n]=bsa[e];
  }
}

// Edge work for one layer, decomposed: only the e@Wf3 / e@Ws3 GEMM (K=128) per edge,
// plus gathered A[dst]+B[src] epilogue, activations, and atomic scatter into hacc[dst].
// e is recomputed on the fly from edge_attr (K=3), staged in LDS.
__global__ __launch_bounds__(256) void k_cgconv2(
    const float* __restrict__ eattr,
    const float* __restrict__ W_edge, const float* __restrict__ b_edge,
    const int* __restrict__ ei,
    const float* __restrict__ Wf3, const float* __restrict__ Ws3,
    const float* __restrict__ Af, const float* __restrict__ Bf,
    const float* __restrict__ As, const float* __restrict__ Bs,
    float* __restrict__ hacc)
{
  __shared__ float4 et[32*32];   // [edge][k4] : 128 floats per edge = 16KB
  __shared__ int s_src[32], s_dst[32];
  int t = threadIdx.x;
  int e0 = blockIdx.x * 32;
  if (t < 32) { s_src[t] = ei[e0+t]; s_dst[t] = ei[NE + e0 + t]; }
  for (int i = t; i < 32*32; i += 256) {
    int el = i >> 5, k4 = i & 31;
    int cc = k4*4, eg = e0 + el;
    float a0 = eattr[eg*3+0], a1 = eattr[eg*3+1], a2 = eattr[eg*3+2];
    float4 w0 = *(const float4*)&W_edge[0*HDIM+cc];
    float4 w1 = *(const float4*)&W_edge[1*HDIM+cc];
    float4 w2 = *(const float4*)&W_edge[2*HDIM+cc];
    float4 bb = *(const float4*)&b_edge[cc];
    float4 v;
    v.x = fmaxf(fmaf(a0,w0.x,fmaf(a1,w1.x,fmaf(a2,w2.x,bb.x))), 0.0f);
    v.y = fmaxf(fmaf(a0,w0.y,fmaf(a1,w1.y,fmaf(a2,w2.y,bb.y))), 0.0f);
    v.z = fmaxf(fmaf(a0,w0.z,fmaf(a1,w1.z,fmaf(a2,w2.z,bb.z))), 0.0f);
    v.w = fmaxf(fmaf(a0,w0.w,fmaf(a1,w1.w,fmaf(a2,w2.w,bb.w))), 0.0f);
    et[i] = v;
  }
  __syncthreads();
  int c = t & 127, g = t >> 7;
  float accf[16], accs[16];
  #pragma unroll
  for (int e=0;e<16;e++){ accf[e]=0.0f; accs[e]=0.0f; }
  const float* wfc = Wf3 + c;
  const float* wsc = Ws3 + c;
  const float4* zb = &et[(g*16)*32];
  for (int k4=0;k4<32;k4++){
    int kk = (k4*4)*HDIM;
    float wf0 = wfc[kk], wf1 = wfc[kk+HDIM], wf2 = wfc[kk+2*HDIM], wf3 = wfc[kk+3*HDIM];
    float ws0 = wsc[kk], ws1 = wsc[kk+HDIM], ws2 = wsc[kk+2*HDIM], ws3 = wsc[kk+3*HDIM];
    #pragma unroll
    for (int e=0;e<16;e++){
      float4 zv = zb[e*32 + k4];
      accf[e] = fmaf(zv.x,wf0,fmaf(zv.y,wf1,fmaf(zv.z,wf2,fmaf(zv.w,wf3,accf[e]))));
      accs[e] = fmaf(zv.x,ws0,fmaf(zv.y,ws1,fmaf(zv.z,ws2,fmaf(zv.w,ws3,accs[e]))));
    }
  }
  #pragma unroll
  for (int e=0;e<16;e++){
    int d = s_dst[g*16+e], s = s_src[g*16+e];
    float f  = accf[e] + Af[(size_t)d*HDIM + c] + Bf[(size_t)s*HDIM + c];
    float sv = accs[e] + As[(size_t)d*HDIM + c] + Bs[(size_t)s*HDIM + c];
    float msg = sigmoidf_(f) * softplusf_(sv);
    atomicAdd(&hacc[(size_t)d*HDIM + c], msg);
  }
}

// h_new = relu(BN(hacc)) (+ h_in if addres); write into h and hacc (next layer's residual base)
__global__ __launch_bounds__(256) void k_bn(
    const float* __restrict__ hacc, const float* __restrict__ hin,
    const float* __restrict__ gam, const float* __restrict__ bet,
    const float* __restrict__ mu, const float* __restrict__ var,
    float* __restrict__ hout, float* __restrict__ haccout, int addres)
{
  int i = blockIdx.x*256 + threadIdx.x;
  if (i >= NN*HDIM) return;
  int c = i & 127;
  float scale = gam[c]*rsqrtf(var[c]+EPSV);
  float tv = (hacc[i]-mu[c])*scale + bet[c];
  tv = fmaxf(tv, 0.0f);
  if (addres) tv += hin[i];
  hout[i] = tv; haccout[i] = tv;
}

__global__ __launch_bounds__(256) void k_pool(
    const float* __restrict__ h, const int* __restrict__ batch,
    float* __restrict__ psum, float* __restrict__ pmax, float* __restrict__ pcnt)
{
  int i = blockIdx.x*256 + threadIdx.x;
  if (i >= NN*HDIM) return;
  int n = i >> 7, c = i & 127;
  int b = batch[n];
  float v = h[i];
  atomicAdd(&psum[b*HDIM+c], v);
  atomicMax((unsigned int*)&pmax[b*HDIM+c], __float_as_uint(v));  // valid: v >= 0
  if (c == 0) atomicAdd(&pcnt[b], 1.0f);
}

// g = [mean|max|sum]; g1 = relu(BN1(g @ W1 + b1))   [256,256]
__global__ __launch_bounds__(256) void k_mlp1(
    const float* __restrict__ psum, const float* __restrict__ pmax, const float* __restrict__ pcnt,
    const float* __restrict__ W1, const float* __restrict__ b1,
    const float* __restrict__ g1g, const float* __restrict__ g1b,
    const float* __restrict__ g1m, const float* __restrict__ g1v,
    float* __restrict__ out)
{
  int i = blockIdx.x*256 + threadIdx.x;
  int g = i >> 8, c = i & 255;
  float inv = 1.0f / fmaxf(pcnt[g], 1.0f);
  float acc = b1[c];
  for (int k=0;k<HDIM;k++) acc = fmaf(psum[g*HDIM+k]*inv, W1[k*256+c], acc);
  for (int k=0;k<HDIM;k++) acc = fmaf(pmax[g*HDIM+k],     W1[(HDIM+k)*256+c], acc);
  for (int k=0;k<HDIM;k++) acc = fmaf(psum[g*HDIM+k],     W1[(2*HDIM+k)*256+c], acc);
  float scale = g1g[c]*rsqrtf(g1v[c]+EPSV);
  acc = (acc - g1m[c])*scale + g1b[c];
  out[i] = fmaxf(acc, 0.0f);
}

// g2 = relu(BN2(g1 @ W2 + b2))   [256,128]
__global__ __launch_bounds__(256) void k_mlp2(
    const float* __restrict__ g1, const float* __restrict__ W2, const float* __restrict__ b2,
    const float* __restrict__ g2g, const float* __restrict__ g2b,
    const float* __restrict__ g2m, const float* __restrict__ g2v,
    float* __restrict__ out)
{
  int i = blockIdx.x*256 + threadIdx.x;
  int g = i >> 7, c = i & 127;
  float acc = b2[c];
  for (int k=0;k<256;k++) acc = fmaf(g1[g*256+k], W2[k*HDIM+c], acc);
  float scale = g2g[c]*rsqrtf(g2v[c]+EPSV);
  acc = (acc - g2m[c])*scale + g2b[c];
  out[i] = fmaxf(acc, 0.0f);
}

// g3 = relu(g2 @ W3 + b3)   [256,64]
__global__ __launch_bounds__(256) void k_mlp3(
    const float* __restrict__ g2, const float* __restrict__ W3, const float* __restrict__ b3,
    float* __restrict__ out)
{
  int i = blockIdx.x*256 + threadIdx.x;
  int g = i >> 6, c = i & 63;
  float acc = b3[c];
  for (int k=0;k<HDIM;k++) acc = fmaf(g2[g*HDIM+k], W3[k*64+c], acc);
  out[i] = fmaxf(acc, 0.0f);
}

__global__ __launch_bounds__(256) void k_heads(
    const float* __restrict__ g3,
    const float* __restrict__ Wv, const float* __restrict__ bv,
    const float* __restrict__ We, const float* __restrict__ be,
    const float* __restrict__ Wd, const float* __restrict__ bd,
    const float* __restrict__ Wh, const float* __restrict__ bh,
    float* __restrict__ out)
{
  int g = blockIdx.x*256 + threadIdx.x;
  if (g >= NG) return;
  float a0=bv[0], a1=be[0], a2=bd[0], a3=bh[0];
  for (int k=0;k<64;k++){
    float xv = g3[g*64+k];
    a0 = fmaf(xv, Wv[k], a0);
    a1 = fmaf(xv, We[k], a1);
    a2 = fmaf(xv, Wd[k], a2);
    a3 = fmaf(xv, Wh[k], a3);
  }
  out[g] = a0; out[NG+g] = a1; out[2*NG+g] = a2; out[3*NG+g] = a3;
}

extern "C" void kernel_launch(void* const* d_in, const int* in_sizes, int n_in,
                              void* d_out, int out_size, void* d_ws, size_t ws_size,
                              hipStream_t stream)
{
  const float* x         = (const float*)d_in[0];
  const float* edge_attr = (const float*)d_in[1];
  const int*   ei        = (const int*)d_in[2];
  const int*   batch     = (const int*)d_in[3];
  const float* W_node    = (const float*)d_in[4];
  const float* b_node    = (const float*)d_in[5];
  const float* W_edge    = (const float*)d_in[6];
  const float* b_edge    = (const float*)d_in[7];
  const float* Wf        = (const float*)d_in[8];
  const float* bf        = (const float*)d_in[9];
  const float* Ws        = (const float*)d_in[10];
  const float* bs        = (const float*)d_in[11];
  const float* bn_g      = (const float*)d_in[12];
  const float* bn_b      = (const float*)d_in[13];
  const float* bn_m      = (const float*)d_in[14];
  const float* bn_v      = (const float*)d_in[15];
  const float* W1        = (const float*)d_in[16];
  const float* b1        = (const float*)d_in[17];
  const float* bn1_g     = (const float*)d_in[18];
  const float* bn1_b     = (const float*)d_in[19];
  const float* bn1_m     = (const float*)d_in[20];
  const float* bn1_v     = (const float*)d_in[21];
  const float* W2        = (const float*)d_in[22];
  const float* b2        = (const float*)d_in[23];
  const float* bn2_g     = (const float*)d_in[24];
  const float* bn2_b     = (const float*)d_in[25];
  const float* bn2_m     = (const float*)d_in[26];
  const float* bn2_v     = (const float*)d_in[27];
  const float* W3        = (const float*)d_in[28];
  const float* b3        = (const float*)d_in[29];
  const float* Wv        = (const float*)d_in[30];
  const float* bv        = (const float*)d_in[31];
  const float* W_en      = (const float*)d_in[32];
  const float* b_en      = (const float*)d_in[33];
  const float* Wd        = (const float*)d_in[34];
  const float* bd        = (const float*)d_in[35];
  const float* Wh        = (const float*)d_in[36];
  const float* bh        = (const float*)d_in[37];

  float* ws   = (float*)d_ws;
  float* h    = ws;                         // 2,560,000
  float* hacc = h    + 2560000;
  float* Af   = hacc + 2560000;
  float* Bf   = Af   + 2560000;
  float* As   = Bf   + 2560000;
  float* Bs   = As   + 2560000;
  float* psum = Bs   + 2560000;             // 32768
  float* pmax = psum + 32768;               // 32768
  float* pcnt = pmax + 32768;               // 256
  float* g1   = pcnt + 256;                 // 65536
  float* g2   = g1 + 65536;                 // 32768
  float* g3   = g2 + 32768;                 // 16384

  k_embed_node<<<(NN*HDIM+255)/256, 256, 0, stream>>>(x, W_node, b_node, h, hacc);
  hipMemsetAsync(psum, 0, (size_t)(32768+32768+256)*sizeof(float), stream);

  for (int i=0;i<10;i++){
    const float* Wfi = Wf + (size_t)i*384*HDIM;
    const float* Wsi = Ws + (size_t)i*384*HDIM;
    k_nodeproj<<<NN/16, 256, 0, stream>>>(h, Wfi, bf + i*HDIM, Wsi, bs + i*HDIM,
        Af, Bf, As, Bs);
    k_cgconv2<<<NE/32, 256, 0, stream>>>(edge_attr, W_edge, b_edge, ei,
        Wfi + 256*HDIM, Wsi + 256*HDIM, Af, Bf, As, Bs, hacc);
    k_bn<<<(NN*HDIM+255)/256, 256, 0, stream>>>(hacc, h,
        bn_g + i*HDIM, bn_b + i*HDIM, bn_m + i*HDIM, bn_v + i*HDIM, h, hacc, i&1);
  }

  k_pool<<<(NN*HDIM+255)/256, 256, 0, stream>>>(h, batch, psum, pmax, pcnt);
  k_mlp1<<<(NG*256)/256, 256, 0, stream>>>(psum, pmax, pcnt, W1, b1, bn1_g, bn1_b, bn1_m, bn1_v, g1);
  k_mlp2<<<(NG*128)/256, 256, 0, stream>>>(g1, W2, b2, bn2_g, bn2_b, bn2_m, bn2_v, g2);
  k_mlp3<<<(NG*64)/256, 256, 0, stream>>>(g2, W3, b3, g3);
  k_heads<<<1, 256, 0, stream>>>(g3, Wv, bv, W_en, b_en, Wd, bd, Wh, bh, (float*)d_out);
}

// Round 6
// 1923.784 us; speedup vs baseline: 2.7842x; 1.6300x over previous
//
#include <hip/hip_runtime.h>
#include <hip/hip_bf16.h>
#include <math.h>

#define NN 20000
#define NE 160000
#define NG 256
#define EPSV 1e-5f

typedef short bf16x8 __attribute__((ext_vector_type(8)));
typedef float f32x4 __attribute__((ext_vector_type(4)));

__device__ __forceinline__ float sigmoidf_(float x){ return 1.0f/(1.0f+__expf(-x)); }
__device__ __forceinline__ float softplusf_(float x){ return fmaxf(x,0.0f) + log1pf(__expf(-fabsf(x))); }
__device__ __forceinline__ unsigned short f2bf(float f){
  unsigned int u = __float_as_uint(f);
  unsigned int r = (u + 0x7fffu + ((u>>16)&1u)) >> 16;
  return (unsigned short)r;
}
__device__ __forceinline__ float bf2f(unsigned short h){
  return __uint_as_float(((unsigned int)h) << 16);
}

// ---- one-time: pack e-part weight blocks (rows 256..383) into MFMA B-frag layout,
// COMPENSATED bf16: hi = bf16(w), lo = bf16(w - hi).
// matrix id m = L*2+g (g: 0=f, 1=s), m in 0..19.
// frag (nt,ks): lane l takes B[k=ks*32+(l>>4)*8+j][col=nt*16+(l&15)]
__global__ __launch_bounds__(256) void k_pack_w(
    const float* __restrict__ Wf, const float* __restrict__ Ws,
    unsigned short* __restrict__ Wpk_hi, unsigned short* __restrict__ Wpk_lo)
{
  int idx = blockIdx.x*256 + threadIdx.x;   // 20 * 2048 = 40960
  if (idx >= 40960) return;
  int l = idx & 63, ks = (idx>>6)&3, nt = (idx>>8)&7;
  int m = idx >> 11;            // 0..19
  int g = m & 1, L = m >> 1;
  const float* src = (g ? Ws : Wf) + (size_t)L*384*128 + (size_t)256*128;
  size_t off = (size_t)m*16384 + (nt*4+ks)*512 + l*8;
  unsigned short* dh = Wpk_hi + off;
  unsigned short* dl = Wpk_lo + off;
  int col = nt*16 + (l&15), k0 = ks*32 + (l>>4)*8;
  #pragma unroll
  for (int j=0;j<8;j++){
    float w = src[(size_t)(k0 + j)*128 + col];
    unsigned short hi = f2bf(w);
    dh[j] = hi;
    dl[j] = f2bf(w - bf2f(hi));
  }
}

// h = relu(x @ W_node + b_node); also initialize hacc = h (residual/atomic base)
__global__ __launch_bounds__(256) void k_embed_node(
    const float* __restrict__ x, const float* __restrict__ W, const float* __restrict__ b,
    float* __restrict__ h, float* __restrict__ hacc)
{
  int i = blockIdx.x*256 + threadIdx.x;
  if (i >= NN*128) return;
  int n = i >> 7, c = i & 127;
  float acc = b[c];
  const float* xr = x + n*10;
  #pragma unroll
  for (int k=0;k<10;k++) acc = fmaf(xr[k], W[k*128+c], acc);
  acc = fmaxf(acc, 0.0f);
  h[i] = acc; hacc[i] = acc;
}

// Per-node projections (fp32 VALU, proven numerics), interleaved output:
//   Pd[n][c] = (Af, As) = (h@Wf1+bf, h@Ws1+bs)   [gathered by dst]
//   Ps[n][c] = (Bf, Bs) = (h@Wf2,    h@Ws2)      [gathered by src]
__global__ __launch_bounds__(256) void k_nodeproj(
    const float* __restrict__ h,
    const float* __restrict__ Wf, const float* __restrict__ bfv,
    const float* __restrict__ Ws, const float* __restrict__ bsv,
    float* __restrict__ Pd, float* __restrict__ Ps)
{
  __shared__ float4 ht[16*32];   // [node][k4] : 128 floats per node = 8KB
  int t = threadIdx.x;
  int n0 = blockIdx.x * 16;
  for (int i = t; i < 16*32; i += 256) {
    int nl = i >> 5, k4 = i & 31;
    ht[i] = *(const float4*)&h[(size_t)(n0+nl)*128 + k4*4];
  }
  __syncthreads();
  int c = t & 127, g = t >> 7;
  float af[8], bfa[8], as_[8], bsa[8];
  float bf0 = bfv[c], bs0 = bsv[c];
  #pragma unroll
  for (int e=0;e<8;e++){ af[e]=bf0; bfa[e]=0.0f; as_[e]=bs0; bsa[e]=0.0f; }
  const float* wA = Wf + c;            // Wf1 col c
  const float* wB = Wf + 128*128 + c;  // Wf2 col c
  const float* sA = Ws + c;
  const float* sB = Ws + 128*128 + c;
  const float4* hb = &ht[(g*8)*32];
  for (int k4=0;k4<32;k4++){
    int kk = (k4*4)*128;
    float a0=wA[kk], a1=wA[kk+128], a2=wA[kk+2*128], a3=wA[kk+3*128];
    float b0=wB[kk], b1=wB[kk+128], b2=wB[kk+2*128], b3=wB[kk+3*128];
    float c0=sA[kk], c1=sA[kk+128], c2=sA[kk+2*128], c3=sA[kk+3*128];
    float d0=sB[kk], d1=sB[kk+128], d2=sB[kk+2*128], d3=sB[kk+3*128];
    #pragma unroll
    for (int e=0;e<8;e++){
      float4 hv = hb[e*32 + k4];
      af[e]  = fmaf(hv.x,a0,fmaf(hv.y,a1,fmaf(hv.z,a2,fmaf(hv.w,a3,af[e]))));
      bfa[e] = fmaf(hv.x,b0,fmaf(hv.y,b1,fmaf(hv.z,b2,fmaf(hv.w,b3,bfa[e]))));
      as_[e] = fmaf(hv.x,c0,fmaf(hv.y,c1,fmaf(hv.z,c2,fmaf(hv.w,c3,as_[e]))));
      bsa[e] = fmaf(hv.x,d0,fmaf(hv.y,d1,fmaf(hv.z,d2,fmaf(hv.w,d3,bsa[e]))));
    }
  }
  #pragma unroll
  for (int e=0;e<8;e++){
    size_t base = (size_t)(n0 + g*8 + e)*256 + c*2;
    float2 vd = {af[e],  as_[e]};
    float2 vs = {bfa[e], bsa[e]};
    *(float2*)&Pd[base] = vd;
    *(float2*)&Ps[base] = vs;
  }
}

// Edge kernel: e = relu(edge_attr@W_edge+b_edge) into swizzled LDS, split hi/lo bf16.
// Compensated MFMA: e@W ~= e_hi@w_hi + e_hi@w_lo + e_lo@w_hi (error ~2^-18 rel).
// Epilogue: float2 gathers of (Af,As)[dst], (Bf,Bs)[src], fp32 activations,
// atomicAdd into hacc[dst].
__global__ __launch_bounds__(256,2) void k_edge_mfma(
    const float* __restrict__ eattr, const float* __restrict__ W_edge,
    const float* __restrict__ b_edge,
    const unsigned short* __restrict__ Wpk_hi,  // layer base: [f | s]
    const unsigned short* __restrict__ Wpk_lo,
    const int* __restrict__ ei,
    const float* __restrict__ Pd, const float* __restrict__ Ps,
    float* __restrict__ hacc)
{
  __shared__ unsigned short elds_hi[64*128];   // 16KB each, chunk-XOR-swizzled rows
  __shared__ unsigned short elds_lo[64*128];
  int t = threadIdx.x;
  int e0 = blockIdx.x * 64;
  for (int id = t; id < 1024; id += 256) {       // 64 rows x 16 chunks(8 cols)
    int row = id >> 4, ch = id & 15;
    int edge = e0 + row, cc = ch*8;
    float a0 = eattr[edge*3+0], a1 = eattr[edge*3+1], a2 = eattr[edge*3+2];
    int so = row*128 + ((ch ^ (row&7))*8);
    #pragma unroll
    for (int j=0;j<8;j++){
      int c = cc + j;
      float v = fmaf(a0, W_edge[c], fmaf(a1, W_edge[128+c], fmaf(a2, W_edge[256+c], b_edge[c])));
      v = fmaxf(v, 0.0f);
      unsigned short hi = f2bf(v);
      elds_hi[so+j] = hi;
      elds_lo[so+j] = f2bf(v - bf2f(hi));
    }
  }
  __syncthreads();
  int l = t & 63, w = t >> 6;
  int row = w*16 + (l&15);
  bf16x8 ah[4], al[4];
  #pragma unroll
  for (int ks=0;ks<4;ks++){
    int ch = (l>>4) + ks*4;
    int so = row*128 + ((ch ^ (row&7))*8);
    ah[ks] = *(const bf16x8*)(elds_hi + so);
    al[ks] = *(const bf16x8*)(elds_lo + so);
  }
  f32x4 accf[8], accs[8];
#define GATE(ACC, OFF)                                                      \
  {                                                                         \
    const unsigned short* wh = Wpk_hi + (OFF) + l*8;                        \
    const unsigned short* wl = Wpk_lo + (OFF) + l*8;                        \
    _Pragma("unroll")                                                       \
    for (int nt=0; nt<8; nt++){                                             \
      f32x4 c = {0.f,0.f,0.f,0.f};                                          \
      _Pragma("unroll")                                                     \
      for (int ks=0;ks<4;ks++){                                             \
        bf16x8 bh = *(const bf16x8*)(wh + (nt*4+ks)*512);                   \
        bf16x8 bl = *(const bf16x8*)(wl + (nt*4+ks)*512);                   \
        c = __builtin_amdgcn_mfma_f32_16x16x32_bf16(ah[ks], bh, c, 0,0,0);  \
        c = __builtin_amdgcn_mfma_f32_16x16x32_bf16(ah[ks], bl, c, 0,0,0);  \
        c = __builtin_amdgcn_mfma_f32_16x16x32_bf16(al[ks], bh, c, 0,0,0);  \
      }                                                                     \
      ACC[nt] = c;                                                          \
    }                                                                       \
  }
  GATE(accf, 0)
  GATE(accs, 16384)
#undef GATE
  int eb = e0 + w*16, col0 = l & 15, rg = (l>>4)*4;
  #pragma unroll
  for (int r=0;r<4;r++){
    int edge = eb + rg + r;
    int s = ei[edge], d = ei[NE + edge];
    const float* pdp = Pd + (size_t)d*256 + col0*2;
    const float* psp = Ps + (size_t)s*256 + col0*2;
    float* hp = hacc + (size_t)d*128 + col0;
    #pragma unroll
    for (int nt=0; nt<8; nt++){
      float2 pd = *(const float2*)(pdp + nt*32);
      float2 ps = *(const float2*)(psp + nt*32);
      float f  = accf[nt][r] + pd.x + ps.x;
      float sv = accs[nt][r] + pd.y + ps.y;
      atomicAdd(hp + nt*16, sigmoidf_(f)*softplusf_(sv));
    }
  }
}

// h_new = relu(BN(hacc)) (+ h_in if addres); write into h and hacc
__global__ __launch_bounds__(256) void k_bn(
    const float* __restrict__ hacc, const float* __restrict__ hin,
    const float* __restrict__ gam, const float* __restrict__ bet,
    const float* __restrict__ mu, const float* __restrict__ var,
    float* __restrict__ hout, float* __restrict__ haccout, int addres)
{
  int i = blockIdx.x*256 + threadIdx.x;
  if (i >= NN*128) return;
  int c = i & 127;
  float scale = gam[c]*rsqrtf(var[c]+EPSV);
  float tv = (hacc[i]-mu[c])*scale + bet[c];
  tv = fmaxf(tv, 0.0f);
  if (addres) tv += hin[i];
  hout[i] = tv; haccout[i] = tv;
}

__global__ __launch_bounds__(256) void k_pool(
    const float* __restrict__ h, const int* __restrict__ batch,
    float* __restrict__ psum, float* __restrict__ pmax, float* __restrict__ pcnt)
{
  int i = blockIdx.x*256 + threadIdx.x;
  if (i >= NN*128) return;
  int n = i >> 7, c = i & 127;
  int b = batch[n];
  float v = h[i];
  atomicAdd(&psum[b*128+c], v);
  atomicMax((unsigned int*)&pmax[b*128+c], __float_as_uint(v));  // valid: v >= 0
  if (c == 0) atomicAdd(&pcnt[b], 1.0f);
}

__global__ __launch_bounds__(256) void k_mlp1(
    const float* __restrict__ psum, const float* __restrict__ pmax, const float* __restrict__ pcnt,
    const float* __restrict__ W1, const float* __restrict__ b1,
    const float* __restrict__ g1g, const float* __restrict__ g1b,
    const float* __restrict__ g1m, const float* __restrict__ g1v,
    float* __restrict__ out)
{
  int i = blockIdx.x*256 + threadIdx.x;
  int g = i >> 8, c = i & 255;
  float inv = 1.0f / fmaxf(pcnt[g], 1.0f);
  float acc = b1[c];
  for (int k=0;k<128;k++) acc = fmaf(psum[g*128+k]*inv, W1[k*256+c], acc);
  for (int k=0;k<128;k++) acc = fmaf(pmax[g*128+k],     W1[(128+k)*256+c], acc);
  for (int k=0;k<128;k++) acc = fmaf(psum[g*128+k],     W1[(256+k)*256+c], acc);
  float scale = g1g[c]*rsqrtf(g1v[c]+EPSV);
  acc = (acc - g1m[c])*scale + g1b[c];
  out[i] = fmaxf(acc, 0.0f);
}

__global__ __launch_bounds__(256) void k_mlp2(
    const float* __restrict__ g1, const float* __restrict__ W2, const float* __restrict__ b2,
    const float* __restrict__ g2g, const float* __restrict__ g2b,
    const float* __restrict__ g2m, const float* __restrict__ g2v,
    float* __restrict__ out)
{
  int i = blockIdx.x*256 + threadIdx.x;
  int g = i >> 7, c = i & 127;
  float acc = b2[c];
  for (int k=0;k<256;k++) acc = fmaf(g1[g*256+k], W2[k*128+c], acc);
  float scale = g2g[c]*rsqrtf(g2v[c]+EPSV);
  acc = (acc - g2m[c])*scale + g2b[c];
  out[i] = fmaxf(acc, 0.0f);
}

__global__ __launch_bounds__(256) void k_mlp3(
    const float* __restrict__ g2, const float* __restrict__ W3, const float* __restrict__ b3,
    float* __restrict__ out)
{
  int i = blockIdx.x*256 + threadIdx.x;
  int g = i >> 6, c = i & 63;
  float acc = b3[c];
  for (int k=0;k<128;k++) acc = fmaf(g2[g*128+k], W3[k*64+c], acc);
  out[i] = fmaxf(acc, 0.0f);
}

__global__ __launch_bounds__(256) void k_heads(
    const float* __restrict__ g3,
    const float* __restrict__ Wv, const float* __restrict__ bv,
    const float* __restrict__ We, const float* __restrict__ be,
    const float* __restrict__ Wd, const float* __restrict__ bd,
    const float* __restrict__ Wh, const float* __restrict__ bh,
    float* __restrict__ out)
{
  int g = blockIdx.x*256 + threadIdx.x;
  if (g >= NG) return;
  float a0=bv[0], a1=be[0], a2=bd[0], a3=bh[0];
  for (int k=0;k<64;k++){
    float xv = g3[g*64+k];
    a0 = fmaf(xv, Wv[k], a0);
    a1 = fmaf(xv, We[k], a1);
    a2 = fmaf(xv, Wd[k], a2);
    a3 = fmaf(xv, Wh[k], a3);
  }
  out[g] = a0; out[NG+g] = a1; out[2*NG+g] = a2; out[3*NG+g] = a3;
}

extern "C" void kernel_launch(void* const* d_in, const int* in_sizes, int n_in,
                              void* d_out, int out_size, void* d_ws, size_t ws_size,
                              hipStream_t stream)
{
  const float* x         = (const float*)d_in[0];
  const float* edge_attr = (const float*)d_in[1];
  const int*   ei        = (const int*)d_in[2];
  const int*   batch     = (const int*)d_in[3];
  const float* W_node    = (const float*)d_in[4];
  const float* b_node    = (const float*)d_in[5];
  const float* W_edge    = (const float*)d_in[6];
  const float* b_edge    = (const float*)d_in[7];
  const float* Wf        = (const float*)d_in[8];
  const float* bf        = (const float*)d_in[9];
  const float* Ws        = (const float*)d_in[10];
  const float* bs        = (const float*)d_in[11];
  const float* bn_g      = (const float*)d_in[12];
  const float* bn_b      = (const float*)d_in[13];
  const float* bn_m      = (const float*)d_in[14];
  const float* bn_v      = (const float*)d_in[15];
  const float* W1        = (const float*)d_in[16];
  const float* b1        = (const float*)d_in[17];
  const float* bn1_g     = (const float*)d_in[18];
  const float* bn1_b     = (const float*)d_in[19];
  const float* bn1_m     = (const float*)d_in[20];
  const float* bn1_v     = (const float*)d_in[21];
  const float* W2        = (const float*)d_in[22];
  const float* b2        = (const float*)d_in[23];
  const float* bn2_g     = (const float*)d_in[24];
  const float* bn2_b     = (const float*)d_in[25];
  const float* bn2_m     = (const float*)d_in[26];
  const float* bn2_v     = (const float*)d_in[27];
  const float* W3        = (const float*)d_in[28];
  const float* b3        = (const float*)d_in[29];
  const float* Wv        = (const float*)d_in[30];
  const float* bv        = (const float*)d_in[31];
  const float* W_en      = (const float*)d_in[32];
  const float* b_en      = (const float*)d_in[33];
  const float* Wd        = (const float*)d_in[34];
  const float* bd        = (const float*)d_in[35];
  const float* Wh        = (const float*)d_in[36];
  const float* bh        = (const float*)d_in[37];

  float* wsf  = (float*)d_ws;
  float* h    = wsf;                          // 2,560,000
  float* hacc = wsf + 2560000;                // 2,560,000
  float* Pd   = wsf + 5120000;                // 5,120,000 (float2 per elem)
  float* Ps   = wsf + 10240000;               // 5,120,000
  unsigned short* Wpk_hi = (unsigned short*)(wsf + 15360000); // 327,680 shorts
  unsigned short* Wpk_lo = (unsigned short*)(wsf + 15523840); // 327,680 shorts
  float* psum = wsf + 15687680;               // 32768
  float* pmax = psum + 32768;                 // 32768
  float* pcnt = pmax + 32768;                 // 256
  float* g1   = pcnt + 256;                   // 65536
  float* g2   = g1 + 65536;                   // 32768
  float* g3   = g2 + 32768;                   // 16384

  k_pack_w<<<160, 256, 0, stream>>>(Wf, Ws, Wpk_hi, Wpk_lo);
  k_embed_node<<<(NN*128+255)/256, 256, 0, stream>>>(x, W_node, b_node, h, hacc);
  hipMemsetAsync(psum, 0, (size_t)(32768+32768+256)*sizeof(float), stream);

  for (int i=0;i<10;i++){
    const float* Wfi = Wf + (size_t)i*384*128;
    const float* Wsi = Ws + (size_t)i*384*128;
    k_nodeproj<<<NN/16, 256, 0, stream>>>(h, Wfi, bf + i*128, Wsi, bs + i*128, Pd, Ps);
    k_edge_mfma<<<NE/64, 256, 0, stream>>>(edge_attr, W_edge, b_edge,
        Wpk_hi + (size_t)i*2*16384, Wpk_lo + (size_t)i*2*16384, ei, Pd, Ps, hacc);
    k_bn<<<(NN*128+255)/256, 256, 0, stream>>>(hacc, h,
        bn_g + i*128, bn_b + i*128, bn_m + i*128, bn_v + i*128, h, hacc, i&1);
  }

  k_pool<<<(NN*128+255)/256, 256, 0, stream>>>(h, batch, psum, pmax, pcnt);
  k_mlp1<<<(NG*256)/256, 256, 0, stream>>>(psum, pmax, pcnt, W1, b1, bn1_g, bn1_b, bn1_m, bn1_v, g1);
  k_mlp2<<<(NG*128)/256, 256, 0, stream>>>(g1, W2, b2, bn2_g, bn2_b, bn2_m, bn2_v, g2);
  k_mlp3<<<(NG*64)/256, 256, 0, stream>>>(g2, W3, b3, g3);
  k_heads<<<1, 256, 0, stream>>>(g3, Wv, bv, W_en, b_en, Wd, bd, Wh, bh, (float*)d_out);
}